// Round 1
// 226.135 us; speedup vs baseline: 1.0201x; 1.0201x over previous
//
#include <hip/hip_runtime.h>

#define NH 8
#define HD 32
#define NL 4
#define NP 4
#define DM 256
#define LEN_IN_C 13294
#define LQ_C 13294
#define B_C 2
#define M_TOTAL (B_C * LQ_C)           // 26588
#define MT_TILES 1662                  // ceil(26588/16)

typedef __attribute__((ext_vector_type(8))) short short8;
typedef __attribute__((ext_vector_type(4))) float floatx4;
typedef __attribute__((ext_vector_type(2))) float floatx2;

__device__ __forceinline__ unsigned short f2bf(float x) {
    union { float f; unsigned int u; } a; a.f = x;
    unsigned int r = (a.u + 0x7FFFu + ((a.u >> 16) & 1u)) >> 16;
    return (unsigned short)r;
}
__device__ __forceinline__ floatx2 up2(unsigned int u) {
    union { unsigned int u; float f; } lo, hi;
    lo.u = u << 16; hi.u = u & 0xffff0000u;
    floatx2 r; r.x = lo.f; r.y = hi.f; return r;
}
__device__ __forceinline__ unsigned int cvtpk_bf16(float lo, float hi) {
    unsigned int r;
    asm("v_cvt_pk_bf16_f32 %0, %1, %2" : "=v"(r) : "v"(lo), "v"(hi));
    return r;
}

// ---------------------------------------------------------------------------
// Weight conversions + bias fuse + pad/tail zeroing in ONE kernel.
// ---------------------------------------------------------------------------
__device__ __forceinline__ void conv_b_body(const float* __restrict__ W,
                                            unsigned short* __restrict__ Bsw,
                                            int Nsrc, int NTsrc, int NTtotal, int ntOff,
                                            int vblk) {
    const int u = vblk * 256 + threadIdx.x;
    const int lane = u & 63;
    const int unit = u >> 6;
    const int ntl = unit % NTsrc;
    const int kc = unit / NTsrc;
    const int n = ntl * 16 + (lane & 15);
    const int k0 = kc * 32 + (lane >> 4) * 8;
    short8 v;
#pragma unroll
    for (int j = 0; j < 8; ++j)
        v[j] = (short)f2bf(W[(size_t)(k0 + j) * Nsrc + n]);
    ((short8*)Bsw)[(size_t)(kc * NTtotal + ntOff + ntl) * 64 + lane] = v;
}

__global__ __launch_bounds__(256) void conv_weights_kernel(const float* __restrict__ Wv,
                                                           const float* __restrict__ Woff,
                                                           const float* __restrict__ Wattn,
                                                           const float* __restrict__ Wout,
                                                           const float* __restrict__ boff,
                                                           const float* __restrict__ battn,
                                                           unsigned short* __restrict__ BswV,
                                                           unsigned short* __restrict__ BswOA,
                                                           unsigned short* __restrict__ BswO,
                                                           float* __restrict__ fbias,
                                                           unsigned short* __restrict__ value,
                                                           unsigned short* __restrict__ AccSw) {
    const int blk = blockIdx.x;
    if (blk < 32)        conv_b_body(Wv,    BswV,  256, 16, 16, 0,  blk);
    else if (blk < 64)   conv_b_body(Woff,  BswOA, 256, 16, 24, 0,  blk - 32);
    else if (blk < 80)   conv_b_body(Wattn, BswOA, 128,  8, 24, 16, blk - 64);
    else if (blk < 112)  conv_b_body(Wout,  BswO,  256, 16, 16, 0,  blk - 80);
    else if (blk < 114) {
        const int t = (blk - 112) * 256 + threadIdx.x;
        if (t < 384) fbias[t] = (t < 256) ? boff[t] : battn[t - 256];
        else if (t < 416) {
            const int j = t - 384;
            value[-32 + j] = 0;                            // front pad (64 B)
            value[(size_t)M_TOTAL * 256 + j] = 0;          // back pad (64 B)
        }
    } else {
        // zero the tail rows 26588..26591 of AccSw (rt=1661, m=12..15)
        const int idx = threadIdx.x;
        if (idx < 128) {
            const int kc = idx >> 4;
            const int sub = idx & 15;
            const int lane = (12 + (sub & 3)) + 16 * (sub >> 2);
            const size_t unit = (size_t)(1661 * 8 + kc) * 64 + lane;
            short8 z = (short8){0, 0, 0, 0, 0, 0, 0, 0};
            ((short8*)AccSw)[unit] = z;
        }
    }
}

// ---------------------------------------------------------------------------
// MFMA GEMM with fp32 row-major A (inline f32->bf16 pack via v_cvt_pk_bf16_f32).
// OUTMODE 0: fp32 row-major [M, NT*16].  OUTMODE 1: bf16 head-major value
//   layout value[((b*8+h)*LEN + pos)*32 + d].
// ---------------------------------------------------------------------------
template <int NT, int OUTMODE>
__global__ __launch_bounds__(256) void mfma_gemm_f32a(const float* __restrict__ A,
                                                      const unsigned short* __restrict__ Bsw,
                                                      const float* __restrict__ bias,
                                                      void* __restrict__ Cout, int M) {
    constexpr int NTW = NT / 4;
    const int tid = threadIdx.x;
    const int lane = tid & 63;
    const int wave = tid >> 6;
    const int rt0 = blockIdx.x * 2;
    const int m = lane & 15;
    const int q = lane >> 4;

    // clamped row pointers: OOB rows duplicate row M-1; stores are guarded.
    const float* Ar0 = A + (size_t)min(rt0 * 16 + m, M - 1) * 256 + q * 8;
    const float* Ar1 = A + (size_t)min(rt0 * 16 + 16 + m, M - 1) * 256 + q * 8;
    const short8* Bu = (const short8*)Bsw;

    floatx4 acc[2][NTW];
#pragma unroll
    for (int r = 0; r < 2; ++r)
#pragma unroll
        for (int t = 0; t < NTW; ++t) acc[r][t] = (floatx4){0.f, 0.f, 0.f, 0.f};

#pragma unroll 2
    for (int kc = 0; kc < 8; ++kc) {
        const float4 f00 = *(const float4*)(Ar0 + kc * 32);
        const float4 f01 = *(const float4*)(Ar0 + kc * 32 + 4);
        const float4 f10 = *(const float4*)(Ar1 + kc * 32);
        const float4 f11 = *(const float4*)(Ar1 + kc * 32 + 4);
        union { uint4 u; short8 s; } c0, c1;
        c0.u.x = cvtpk_bf16(f00.x, f00.y); c0.u.y = cvtpk_bf16(f00.z, f00.w);
        c0.u.z = cvtpk_bf16(f01.x, f01.y); c0.u.w = cvtpk_bf16(f01.z, f01.w);
        c1.u.x = cvtpk_bf16(f10.x, f10.y); c1.u.y = cvtpk_bf16(f10.z, f10.w);
        c1.u.z = cvtpk_bf16(f11.x, f11.y); c1.u.w = cvtpk_bf16(f11.z, f11.w);
        const short8 a0 = c0.s;
        const short8 a1 = c1.s;
#pragma unroll
        for (int t = 0; t < NTW; ++t) {
            const short8 b = Bu[(size_t)(kc * NT + wave * NTW + t) * 64 + lane];
            acc[0][t] = __builtin_amdgcn_mfma_f32_16x16x32_bf16(a0, b, acc[0][t], 0, 0, 0);
            acc[1][t] = __builtin_amdgcn_mfma_f32_16x16x32_bf16(a1, b, acc[1][t], 0, 0, 0);
        }
    }

    const int N = NT * 16;
    const int colq = lane & 15;
    const int rowq = (lane >> 4) * 4;
#pragma unroll
    for (int t = 0; t < NTW; ++t) {
        const int col = (wave * NTW + t) * 16 + colq;
        const float bc = bias[col];
#pragma unroll
        for (int r = 0; r < 2; ++r) {
            const int rowb = (rt0 + r) * 16 + rowq;
#pragma unroll
            for (int reg = 0; reg < 4; ++reg) {
                const int row = rowb + reg;
                if (row < M) {
                    const float v = acc[r][t][reg] + bc;
                    if (OUTMODE == 1) {
                        const int bb = row >= LEN_IN_C;
                        const int pos = row - (bb ? LEN_IN_C : 0);
                        const int hh = col >> 5;
                        const int dd = col & 31;
                        ((unsigned short*)Cout)[((size_t)((bb << 3) + hh) * LEN_IN_C + pos) * 32 + dd] = f2bf(v);
                    } else {
                        ((float*)Cout)[(size_t)row * N + col] = v;
                    }
                }
            }
        }
    }
}

// ---------------------------------------------------------------------------
// Register-only MFMA GEMM with pre-swizzled bf16 A (final projection).
// ---------------------------------------------------------------------------
template <int NT, bool OUT_BF16>
__global__ __launch_bounds__(256) void mfma_gemm_kernel(const unsigned short* __restrict__ Asw,
                                                        const unsigned short* __restrict__ Bsw,
                                                        const float* __restrict__ bias,
                                                        void* __restrict__ Cout, int M) {
    constexpr int NTW = NT / 4;
    const int tid = threadIdx.x;
    const int lane = tid & 63;
    const int wave = tid >> 6;
    const int rt0 = blockIdx.x * 2;

    const short8* Au = (const short8*)Asw;
    const short8* Bu = (const short8*)Bsw;

    floatx4 acc[2][NTW];
#pragma unroll
    for (int r = 0; r < 2; ++r)
#pragma unroll
        for (int t = 0; t < NTW; ++t) acc[r][t] = (floatx4){0.f, 0.f, 0.f, 0.f};

#pragma unroll 2
    for (int kc = 0; kc < 8; ++kc) {
        const short8 a0 = Au[(size_t)(rt0 * 8 + kc) * 64 + lane];
        const short8 a1 = Au[(size_t)((rt0 + 1) * 8 + kc) * 64 + lane];
#pragma unroll
        for (int t = 0; t < NTW; ++t) {
            const short8 b = Bu[(size_t)(kc * NT + wave * NTW + t) * 64 + lane];
            acc[0][t] = __builtin_amdgcn_mfma_f32_16x16x32_bf16(a0, b, acc[0][t], 0, 0, 0);
            acc[1][t] = __builtin_amdgcn_mfma_f32_16x16x32_bf16(a1, b, acc[1][t], 0, 0, 0);
        }
    }

    const int N = NT * 16;
    const int colq = lane & 15;
    const int rowq = (lane >> 4) * 4;
#pragma unroll
    for (int t = 0; t < NTW; ++t) {
        const int col = (wave * NTW + t) * 16 + colq;
        const float bc = bias[col];
#pragma unroll
        for (int r = 0; r < 2; ++r) {
            const int rowb = (rt0 + r) * 16 + rowq;
#pragma unroll
            for (int reg = 0; reg < 4; ++reg) {
                const int row = rowb + reg;
                if (row < M) {
                    const float v = acc[r][t][reg] + bc;
                    if (OUT_BF16)
                        ((unsigned short*)Cout)[(size_t)row * N + col] = f2bf(v);
                    else
                        ((float*)Cout)[(size_t)row * N + col] = v;
                }
            }
        }
    }
}

// ---------------------------------------------------------------------------
// Sampler v4: head-major value layout -> pair loads.
//   Phase 1: 512 point-jobs compute softmax + TWO row-pair byte offsets
//            (top/bottom) + 4 premult weights -> LDS.
//   Phase 2: tid = qq*64 + h*8 + l8. 8 lanes x dwordx4 = 128 B = BOTH
//            horizontal corners of one row. l8<4 -> left corner (w00/w10),
//            l8>=4 -> right corner (w01/w11). Packed float2 accumulate
//            (v_pk_fma_f32), one shfl_xor(4) reduce, one uint4 store into
//            the swizzled A-fragment layout.
// ---------------------------------------------------------------------------
__global__ __launch_bounds__(256, 8) void msda_sample_kernel(const float* __restrict__ refp,
                                                             const unsigned short* __restrict__ value,
                                                             const float* __restrict__ fused,
                                                             unsigned short* __restrict__ AccSw) {
    constexpr int lvl_hw[4] = {100, 50, 25, 13};
    constexpr int lvl_s[4] = {0, 10000, 12500, 13125};

    const int bq0 = blockIdx.x * 4;
    const int tid = threadIdx.x;

    __shared__ float s_ref[32];
    __shared__ int2 s_pi[4 * 8 * 17];
    __shared__ float4 s_pw[4 * 8 * 17];

    if (tid < 32) s_ref[tid] = refp[(size_t)bq0 * 8 + tid];
    __syncthreads();

#pragma unroll
    for (int jj = 0; jj < 2; ++jj) {
        const int job = jj * 256 + tid;          // 0..511
        const int qq = job >> 7;                 // 0..3
        const int t = job & 127;                 // point id within query
        const int h = t >> 4;
        const int l = (t >> 2) & 3;
        const int bq = bq0 + qq;
        const int b = (bq >= LQ_C) ? 1 : 0;

        // softmax over the 16 (l,p) logits of head h
        const float logit = fused[(size_t)bq * 384 + 256 + t];
        float m = logit;
#pragma unroll
        for (int mask = 1; mask < 16; mask <<= 1) m = fmaxf(m, __shfl_xor(m, mask));
        const float e = expf(logit - m);
        float s = e;
#pragma unroll
        for (int mask = 1; mask < 16; mask <<= 1) s += __shfl_xor(s, mask);
        const float aw = e / s;

        const int whl = lvl_hw[l];
        const float fwh = (float)whl;
        const float2 oxy = *(const float2*)(fused + (size_t)bq * 384 + t * 2);
        const float x = s_ref[qq * 8 + l * 2] * fwh + oxy.x - 0.5f;
        const float y = s_ref[qq * 8 + l * 2 + 1] * fwh + oxy.y - 0.5f;
        const float x0f = floorf(x), y0f = floorf(y);
        const float tx = x - x0f, ty = y - y0f;
        const int ix0 = (int)x0f, iy0 = (int)y0f;

        const bool xv0 = (unsigned)ix0 < (unsigned)whl;
        const bool xv1 = (unsigned)(ix0 + 1) < (unsigned)whl;
        const bool yv0 = (unsigned)iy0 < (unsigned)whl;
        const bool yv1 = (unsigned)(iy0 + 1) < (unsigned)whl;

        // pair base x: clamp to [-1, w-1]; invalid halves carry zero weight
        const int cxp = min(max(ix0, -1), whl - 1);
        const int cy0 = min(max(iy0, 0), whl - 1);
        const int cy1 = min(max(iy0 + 1, 0), whl - 1);

        const int posb = (b * 8 + h) * LEN_IN_C + lvl_s[l];
        int2 aa;                                  // BYTE offsets of 128-B pairs
        aa.x = (posb + cy0 * whl + cxp) * 64;
        aa.y = (posb + cy1 * whl + cxp) * 64;
        float4 wv;
        wv.x = (xv0 && yv0) ? aw * (1.f - tx) * (1.f - ty) : 0.f;
        wv.y = (xv1 && yv0) ? aw * tx * (1.f - ty) : 0.f;
        wv.z = (xv0 && yv1) ? aw * (1.f - tx) * ty : 0.f;
        wv.w = (xv1 && yv1) ? aw * tx * ty : 0.f;
        const int slot = (qq * 8 + h) * 17 + (t & 15);
        s_pi[slot] = aa;
        s_pw[slot] = wv;
    }
    __syncthreads();

    const int qq = tid >> 6;
    const int h = (tid >> 3) & 7;
    const int l8 = tid & 7;
    const char* vbp = (const char*)value + l8 * 16;
    const int pbase = (qq * 8 + h) * 17;
    const bool right = (l8 & 4) != 0;

    floatx2 acc0 = (floatx2){0.f, 0.f}, acc1 = acc0, acc2 = acc0, acc3 = acc0;
#pragma unroll 2
    for (int pt = 0; pt < 16; ++pt) {
        const int2 aa = s_pi[pbase + pt];
        const float4 wv = s_pw[pbase + pt];
        const float wt = right ? wv.y : wv.x;
        const float wb = right ? wv.w : wv.z;
        const uint4 vt = *(const uint4*)(vbp + aa.x);
        const uint4 vbm = *(const uint4*)(vbp + aa.y);
        const floatx2 w2t = (floatx2){wt, wt};
        const floatx2 w2b = (floatx2){wb, wb};
        acc0 += w2t * up2(vt.x);
        acc1 += w2t * up2(vt.y);
        acc2 += w2t * up2(vt.z);
        acc3 += w2t * up2(vt.w);
        acc0 += w2b * up2(vbm.x);
        acc1 += w2b * up2(vbm.y);
        acc2 += w2b * up2(vbm.z);
        acc3 += w2b * up2(vbm.w);
    }

    float r0 = acc0.x, r1 = acc0.y, r2 = acc1.x, r3 = acc1.y;
    float r4 = acc2.x, r5 = acc2.y, r6 = acc3.x, r7 = acc3.y;
    r0 += __shfl_xor(r0, 4); r1 += __shfl_xor(r1, 4);
    r2 += __shfl_xor(r2, 4); r3 += __shfl_xor(r3, 4);
    r4 += __shfl_xor(r4, 4); r5 += __shfl_xor(r5, 4);
    r6 += __shfl_xor(r6, 4); r7 += __shfl_xor(r7, 4);

    if (!right) {
        // write swizzled A-fragment: row = bq, col = h*32 + (l8&3)*8 + (0..7)
        const int bq = bq0 + qq;
        const int rt = bq >> 4, mm = bq & 15;
        const int unit = (rt * 8 + h) * 64 + ((l8 & 3) * 16 + mm);
        uint4 o;
        o.x = cvtpk_bf16(r0, r1);
        o.y = cvtpk_bf16(r2, r3);
        o.z = cvtpk_bf16(r4, r5);
        o.w = cvtpk_bf16(r6, r7);
        *(uint4*)(AccSw + (size_t)unit * 8) = o;
    }
}

extern "C" void kernel_launch(void* const* d_in, const int* in_sizes, int n_in,
                              void* d_out, int out_size, void* d_ws, size_t ws_size,
                              hipStream_t stream) {
    const float* query  = (const float*)d_in[0];
    const float* refp   = (const float*)d_in[1];
    const float* inflat = (const float*)d_in[2];
    const float* Wv    = (const float*)d_in[4];
    const float* bv    = (const float*)d_in[5];
    const float* Woff  = (const float*)d_in[6];
    const float* boff  = (const float*)d_in[7];
    const float* Wattn = (const float*)d_in[8];
    const float* battn = (const float*)d_in[9];
    const float* Wout  = (const float*)d_in[10];
    const float* bout  = (const float*)d_in[11];
    float* out = (float*)d_out;

    char* p = (char*)d_ws;
    unsigned short* AccSw = (unsigned short*)p;
    p += (size_t)MT_TILES * 8 * 64 * 8 * sizeof(unsigned short);          // 13.6 MB
    unsigned short* BswV = (unsigned short*)p;   p += (size_t)8 * 16 * 64 * 8 * 2;
    unsigned short* BswOA = (unsigned short*)p;  p += (size_t)8 * 24 * 64 * 8 * 2;
    unsigned short* BswO = (unsigned short*)p;   p += (size_t)8 * 16 * 64 * 8 * 2;
    float* fbias = (float*)p;                    p += 384 * sizeof(float);
    unsigned short* value = (unsigned short*)p + 32;                      // 64 B front pad
    p += ((size_t)M_TOTAL * 256 + 64) * sizeof(unsigned short);           // + 64 B back pad
    float* fused = (float*)p;                    p += (size_t)M_TOTAL * 384 * 4;

    const int M = M_TOTAL;
    const int gemmBlocks = MT_TILES / 2;    // 831

    conv_weights_kernel<<<115, 256, 0, stream>>>(Wv, Woff, Wattn, Wout, boff, battn,
                                                 BswV, BswOA, BswO, fbias, value, AccSw);
    mfma_gemm_f32a<16, 1><<<gemmBlocks, 256, 0, stream>>>(inflat, BswV, bv, value, M);
    mfma_gemm_f32a<24, 0><<<gemmBlocks, 256, 0, stream>>>(query, BswOA, fbias, fused, M);
    msda_sample_kernel<<<M / 4, 256, 0, stream>>>(refp, value, fused, AccSw);
    mfma_gemm_kernel<16, false><<<gemmBlocks, 256, 0, stream>>>(AccSw, BswO, bout, out, M);
}

// Round 2
// 221.795 us; speedup vs baseline: 1.0400x; 1.0196x over previous
//
#include <hip/hip_runtime.h>

#define NH 8
#define HD 32
#define NL 4
#define NP 4
#define DM 256
#define LEN_IN_C 13294
#define LQ_C 13294
#define B_C 2
#define M_TOTAL (B_C * LQ_C)           // 26588
#define MT_TILES 1662                  // ceil(26588/16)
#define GQ 32                          // queries per sampler block
#define QBLKS 831                      // ceil(26588/32)

typedef __attribute__((ext_vector_type(8))) short short8;
typedef __attribute__((ext_vector_type(4))) float floatx4;
typedef __attribute__((ext_vector_type(2))) float floatx2;

__device__ __forceinline__ unsigned short f2bf(float x) {
    union { float f; unsigned int u; } a; a.f = x;
    unsigned int r = (a.u + 0x7FFFu + ((a.u >> 16) & 1u)) >> 16;
    return (unsigned short)r;
}
__device__ __forceinline__ floatx2 up2(unsigned int u) {
    union { unsigned int u; float f; } lo, hi;
    lo.u = u << 16; hi.u = u & 0xffff0000u;
    floatx2 r; r.x = lo.f; r.y = hi.f; return r;
}
__device__ __forceinline__ unsigned int cvtpk_bf16(float lo, float hi) {
    unsigned int r;
    asm("v_cvt_pk_bf16_f32 %0, %1, %2" : "=v"(r) : "v"(lo), "v"(hi));
    return r;
}

// ---------------------------------------------------------------------------
// Weight conversions + bias fuse + pad/tail zeroing in ONE kernel.
// ---------------------------------------------------------------------------
__device__ __forceinline__ void conv_b_body(const float* __restrict__ W,
                                            unsigned short* __restrict__ Bsw,
                                            int Nsrc, int NTsrc, int NTtotal, int ntOff,
                                            int vblk) {
    const int u = vblk * 256 + threadIdx.x;
    const int lane = u & 63;
    const int unit = u >> 6;
    const int ntl = unit % NTsrc;
    const int kc = unit / NTsrc;
    const int n = ntl * 16 + (lane & 15);
    const int k0 = kc * 32 + (lane >> 4) * 8;
    short8 v;
#pragma unroll
    for (int j = 0; j < 8; ++j)
        v[j] = (short)f2bf(W[(size_t)(k0 + j) * Nsrc + n]);
    ((short8*)Bsw)[(size_t)(kc * NTtotal + ntOff + ntl) * 64 + lane] = v;
}

__global__ __launch_bounds__(256) void conv_weights_kernel(const float* __restrict__ Wv,
                                                           const float* __restrict__ Woff,
                                                           const float* __restrict__ Wattn,
                                                           const float* __restrict__ Wout,
                                                           const float* __restrict__ boff,
                                                           const float* __restrict__ battn,
                                                           unsigned short* __restrict__ BswV,
                                                           unsigned short* __restrict__ BswOA,
                                                           unsigned short* __restrict__ BswO,
                                                           float* __restrict__ fbias,
                                                           unsigned short* __restrict__ value,
                                                           unsigned short* __restrict__ AccSw) {
    const int blk = blockIdx.x;
    if (blk < 32)        conv_b_body(Wv,    BswV,  256, 16, 16, 0,  blk);
    else if (blk < 64)   conv_b_body(Woff,  BswOA, 256, 16, 24, 0,  blk - 32);
    else if (blk < 80)   conv_b_body(Wattn, BswOA, 128,  8, 24, 16, blk - 64);
    else if (blk < 112)  conv_b_body(Wout,  BswO,  256, 16, 16, 0,  blk - 80);
    else if (blk < 114) {
        const int t = (blk - 112) * 256 + threadIdx.x;
        if (t < 384) fbias[t] = (t < 256) ? boff[t] : battn[t - 256];
        else if (t < 416) {
            const int j = t - 384;
            value[-32 + j] = 0;                            // front pad (64 B)
            value[(size_t)M_TOTAL * 256 + j] = 0;          // back pad (64 B)
        }
    } else {
        // zero the tail rows 26588..26591 of AccSw (rt=1661, m=12..15)
        const int idx = threadIdx.x;
        if (idx < 128) {
            const int kc = idx >> 4;
            const int sub = idx & 15;
            const int lane = (12 + (sub & 3)) + 16 * (sub >> 2);
            const size_t unit = (size_t)(1661 * 8 + kc) * 64 + lane;
            short8 z = (short8){0, 0, 0, 0, 0, 0, 0, 0};
            ((short8*)AccSw)[unit] = z;
        }
    }
}

// ---------------------------------------------------------------------------
// MFMA GEMM body, fp32 row-major A, ONE 16-row tile per block (max TLP).
// OUTMODE 0: fp32 row-major [M, NT*16].  OUTMODE 1: bf16 head-major value
//   layout value[((b*8+h)*LEN + pos)*32 + d].
// ---------------------------------------------------------------------------
template <int NT, int OUTMODE>
__device__ __forceinline__ void gemm_f32a_body(const float* __restrict__ A,
                                               const unsigned short* __restrict__ Bsw,
                                               const float* __restrict__ bias,
                                               void* __restrict__ Cout, int M, int rt) {
    constexpr int NTW = NT / 4;
    const int tid = threadIdx.x;
    const int lane = tid & 63;
    const int wave = tid >> 6;
    const int m = lane & 15;
    const int q = lane >> 4;

    const float* Ar = A + (size_t)min(rt * 16 + m, M - 1) * 256 + q * 8;
    const short8* Bu = (const short8*)Bsw;

    floatx4 acc[NTW];
#pragma unroll
    for (int t = 0; t < NTW; ++t) acc[t] = (floatx4){0.f, 0.f, 0.f, 0.f};

#pragma unroll 2
    for (int kc = 0; kc < 8; ++kc) {
        const float4 f0 = *(const float4*)(Ar + kc * 32);
        const float4 f1 = *(const float4*)(Ar + kc * 32 + 4);
        union { uint4 u; short8 s; } c;
        c.u.x = cvtpk_bf16(f0.x, f0.y); c.u.y = cvtpk_bf16(f0.z, f0.w);
        c.u.z = cvtpk_bf16(f1.x, f1.y); c.u.w = cvtpk_bf16(f1.z, f1.w);
        const short8 a = c.s;
#pragma unroll
        for (int t = 0; t < NTW; ++t) {
            const short8 b = Bu[(size_t)(kc * NT + wave * NTW + t) * 64 + lane];
            acc[t] = __builtin_amdgcn_mfma_f32_16x16x32_bf16(a, b, acc[t], 0, 0, 0);
        }
    }

    const int N = NT * 16;
    const int colq = lane & 15;
    const int rowq = (lane >> 4) * 4;
#pragma unroll
    for (int t = 0; t < NTW; ++t) {
        const int col = (wave * NTW + t) * 16 + colq;
        const float bc = bias[col];
#pragma unroll
        for (int reg = 0; reg < 4; ++reg) {
            const int row = rt * 16 + rowq + reg;
            if (row < M) {
                const float v = acc[t][reg] + bc;
                if (OUTMODE == 1) {
                    const int bb = row >= LEN_IN_C;
                    const int pos = row - (bb ? LEN_IN_C : 0);
                    const int hh = col >> 5;
                    const int dd = col & 31;
                    ((unsigned short*)Cout)[((size_t)((bb << 3) + hh) * LEN_IN_C + pos) * 32 + dd] = f2bf(v);
                } else {
                    ((float*)Cout)[(size_t)row * N + col] = v;
                }
            }
        }
    }
}

// Combined front GEMM: even blocks -> value projection, odd -> off/attn GEMM.
// The two independent GEMMs overlap in one launch (2x TLP, one less launch).
__global__ __launch_bounds__(256) void front_gemm_kernel(const float* __restrict__ inflat,
                                                         const float* __restrict__ query,
                                                         const unsigned short* __restrict__ BswV,
                                                         const unsigned short* __restrict__ BswOA,
                                                         const float* __restrict__ bv,
                                                         const float* __restrict__ fbias,
                                                         unsigned short* __restrict__ value,
                                                         float* __restrict__ fused, int M) {
    const int x = blockIdx.x;
    const int rt = x >> 1;
    if ((x & 1) == 0)
        gemm_f32a_body<16, 1>(inflat, BswV, bv, (void*)value, M, rt);
    else
        gemm_f32a_body<24, 0>(query, BswOA, fbias, (void*)fused, M, rt);
}

// ---------------------------------------------------------------------------
// Back GEMM: pre-swizzled bf16 A (sampler output), one 16-row tile per block.
// ---------------------------------------------------------------------------
__global__ __launch_bounds__(256) void back_gemm_kernel(const unsigned short* __restrict__ Asw,
                                                        const unsigned short* __restrict__ Bsw,
                                                        const float* __restrict__ bias,
                                                        float* __restrict__ Cout, int M) {
    constexpr int NT = 16;
    constexpr int NTW = 4;
    const int tid = threadIdx.x;
    const int lane = tid & 63;
    const int wave = tid >> 6;
    const int rt = blockIdx.x;

    const short8* Au = (const short8*)Asw;
    const short8* Bu = (const short8*)Bsw;

    floatx4 acc[NTW];
#pragma unroll
    for (int t = 0; t < NTW; ++t) acc[t] = (floatx4){0.f, 0.f, 0.f, 0.f};

#pragma unroll 2
    for (int kc = 0; kc < 8; ++kc) {
        const short8 a = Au[(size_t)(rt * 8 + kc) * 64 + lane];
#pragma unroll
        for (int t = 0; t < NTW; ++t) {
            const short8 b = Bu[(size_t)(kc * NT + wave * NTW + t) * 64 + lane];
            acc[t] = __builtin_amdgcn_mfma_f32_16x16x32_bf16(a, b, acc[t], 0, 0, 0);
        }
    }

    const int colq = lane & 15;
    const int rowq = (lane >> 4) * 4;
#pragma unroll
    for (int t = 0; t < NTW; ++t) {
        const int col = (wave * NTW + t) * 16 + colq;
        const float bc = bias[col];
#pragma unroll
        for (int reg = 0; reg < 4; ++reg) {
            const int row = rt * 16 + rowq + reg;
            if (row < M)
                Cout[(size_t)row * 256 + col] = acc[t][reg] + bc;
        }
    }
}

// ---------------------------------------------------------------------------
// Sampler v5: head-per-XCD partitioning.
//   One block = 32 queries x 1 head; head = wgid % 8 so (round-robin
//   wgid->XCD) XCD h only touches value[b][h] = 1.7 MB -> fits 4 MB L2.
//   Phase 1: 512 point-jobs (32q x 16 pts): softmax over the head's 16
//     logits (16-lane shfl) + 2 row-pair byte offsets + 4 premult weights.
//   Phase 2: tid = qq*8 + l8; 8 lanes x dwordx4 = 128 B = both horizontal
//     corners of one row; l8<4 left / l8>=4 right; packed float2 FMA;
//     shfl_xor(4) fold; one uint4 store into swizzled A-fragment layout.
// ---------------------------------------------------------------------------
__global__ __launch_bounds__(256, 8) void msda_sample_kernel(const float* __restrict__ refp,
                                                             const unsigned short* __restrict__ value,
                                                             const float* __restrict__ fused,
                                                             unsigned short* __restrict__ AccSw) {
    constexpr int lvl_hw[4] = {100, 50, 25, 13};
    constexpr int lvl_s[4] = {0, 10000, 12500, 13125};

    const int wg = blockIdx.x;
    const int h = wg & 7;
    const int q0 = (wg >> 3) * GQ;
    const int tid = threadIdx.x;

    __shared__ float s_ref[GQ * 8];
    __shared__ int2 s_pi[GQ * 17];
    __shared__ float4 s_pw[GQ * 17];

    s_ref[tid] = refp[min(q0 * 8 + tid, M_TOTAL * 8 - 1)];
    __syncthreads();

#pragma unroll
    for (int jj = 0; jj < 2; ++jj) {
        const int job = jj * 256 + tid;          // 0..511
        const int qq = job >> 4;                 // 0..31
        const int t16 = job & 15;                // l*4+p
        const int l = t16 >> 2;
        const int bq = min(q0 + qq, M_TOTAL - 1);
        const int b = (bq >= LQ_C) ? 1 : 0;

        // softmax over the 16 (l,p) logits of head h (16 consecutive lanes)
        const float logit = fused[(size_t)bq * 384 + 256 + h * 16 + t16];
        float m = logit;
#pragma unroll
        for (int mask = 1; mask < 16; mask <<= 1) m = fmaxf(m, __shfl_xor(m, mask));
        const float e = expf(logit - m);
        float s = e;
#pragma unroll
        for (int mask = 1; mask < 16; mask <<= 1) s += __shfl_xor(s, mask);
        const float aw = e / s;

        const int whl = lvl_hw[l];
        const float fwh = (float)whl;
        const float2 oxy = *(const float2*)(fused + (size_t)bq * 384 + (h * 16 + t16) * 2);
        const float x = s_ref[qq * 8 + l * 2] * fwh + oxy.x - 0.5f;
        const float y = s_ref[qq * 8 + l * 2 + 1] * fwh + oxy.y - 0.5f;
        const float x0f = floorf(x), y0f = floorf(y);
        const float tx = x - x0f, ty = y - y0f;
        const int ix0 = (int)x0f, iy0 = (int)y0f;

        const bool xv0 = (unsigned)ix0 < (unsigned)whl;
        const bool xv1 = (unsigned)(ix0 + 1) < (unsigned)whl;
        const bool yv0 = (unsigned)iy0 < (unsigned)whl;
        const bool yv1 = (unsigned)(iy0 + 1) < (unsigned)whl;

        // pair base x: clamp to [-1, w-1]; invalid halves carry zero weight
        const int cxp = min(max(ix0, -1), whl - 1);
        const int cy0 = min(max(iy0, 0), whl - 1);
        const int cy1 = min(max(iy0 + 1, 0), whl - 1);

        const int posb = (b * 8 + h) * LEN_IN_C + lvl_s[l];
        int2 aa;                                  // BYTE offsets of 128-B pairs
        aa.x = (posb + cy0 * whl + cxp) * 64;
        aa.y = (posb + cy1 * whl + cxp) * 64;
        float4 wv;
        wv.x = (xv0 && yv0) ? aw * (1.f - tx) * (1.f - ty) : 0.f;
        wv.y = (xv1 && yv0) ? aw * tx * (1.f - ty) : 0.f;
        wv.z = (xv0 && yv1) ? aw * (1.f - tx) * ty : 0.f;
        wv.w = (xv1 && yv1) ? aw * tx * ty : 0.f;
        const int slot = qq * 17 + t16;
        s_pi[slot] = aa;
        s_pw[slot] = wv;
    }
    __syncthreads();

    const int qq = tid >> 3;
    const int l8 = tid & 7;
    const char* vbp = (const char*)value + l8 * 16;
    const int pbase = qq * 17;
    const bool right = (l8 & 4) != 0;

    floatx2 acc0 = (floatx2){0.f, 0.f}, acc1 = acc0, acc2 = acc0, acc3 = acc0;
#pragma unroll 2
    for (int pt = 0; pt < 16; ++pt) {
        const int2 aa = s_pi[pbase + pt];
        const float4 wv = s_pw[pbase + pt];
        const float wt = right ? wv.y : wv.x;
        const float wb = right ? wv.w : wv.z;
        const uint4 vt = *(const uint4*)(vbp + aa.x);
        const uint4 vbm = *(const uint4*)(vbp + aa.y);
        const floatx2 w2t = (floatx2){wt, wt};
        const floatx2 w2b = (floatx2){wb, wb};
        acc0 += w2t * up2(vt.x);
        acc1 += w2t * up2(vt.y);
        acc2 += w2t * up2(vt.z);
        acc3 += w2t * up2(vt.w);
        acc0 += w2b * up2(vbm.x);
        acc1 += w2b * up2(vbm.y);
        acc2 += w2b * up2(vbm.z);
        acc3 += w2b * up2(vbm.w);
    }

    float r0 = acc0.x, r1 = acc0.y, r2 = acc1.x, r3 = acc1.y;
    float r4 = acc2.x, r5 = acc2.y, r6 = acc3.x, r7 = acc3.y;
    r0 += __shfl_xor(r0, 4); r1 += __shfl_xor(r1, 4);
    r2 += __shfl_xor(r2, 4); r3 += __shfl_xor(r3, 4);
    r4 += __shfl_xor(r4, 4); r5 += __shfl_xor(r5, 4);
    r6 += __shfl_xor(r6, 4); r7 += __shfl_xor(r7, 4);

    const int bq = q0 + qq;
    if (!right && bq < M_TOTAL) {
        // write swizzled A-fragment: row = bq, col = h*32 + (l8&3)*8 (+0..7)
        const int rt = bq >> 4, mm = bq & 15;
        const int unit = (rt * 8 + h) * 64 + ((l8 & 3) * 16 + mm);
        uint4 o;
        o.x = cvtpk_bf16(r0, r1);
        o.y = cvtpk_bf16(r2, r3);
        o.z = cvtpk_bf16(r4, r5);
        o.w = cvtpk_bf16(r6, r7);
        *(uint4*)(AccSw + (size_t)unit * 8) = o;
    }
}

extern "C" void kernel_launch(void* const* d_in, const int* in_sizes, int n_in,
                              void* d_out, int out_size, void* d_ws, size_t ws_size,
                              hipStream_t stream) {
    const float* query  = (const float*)d_in[0];
    const float* refp   = (const float*)d_in[1];
    const float* inflat = (const float*)d_in[2];
    const float* Wv    = (const float*)d_in[4];
    const float* bv    = (const float*)d_in[5];
    const float* Woff  = (const float*)d_in[6];
    const float* boff  = (const float*)d_in[7];
    const float* Wattn = (const float*)d_in[8];
    const float* battn = (const float*)d_in[9];
    const float* Wout  = (const float*)d_in[10];
    const float* bout  = (const float*)d_in[11];
    float* out = (float*)d_out;

    char* p = (char*)d_ws;
    unsigned short* AccSw = (unsigned short*)p;
    p += (size_t)MT_TILES * 8 * 64 * 8 * sizeof(unsigned short);          // 13.6 MB
    unsigned short* BswV = (unsigned short*)p;   p += (size_t)8 * 16 * 64 * 8 * 2;
    unsigned short* BswOA = (unsigned short*)p;  p += (size_t)8 * 24 * 64 * 8 * 2;
    unsigned short* BswO = (unsigned short*)p;   p += (size_t)8 * 16 * 64 * 8 * 2;
    float* fbias = (float*)p;                    p += 384 * sizeof(float);
    unsigned short* value = (unsigned short*)p + 32;                      // 64 B front pad
    p += ((size_t)M_TOTAL * 256 + 64) * sizeof(unsigned short);           // + 64 B back pad
    float* fused = (float*)p;                    p += (size_t)M_TOTAL * 384 * 4;

    const int M = M_TOTAL;

    conv_weights_kernel<<<115, 256, 0, stream>>>(Wv, Woff, Wattn, Wout, boff, battn,
                                                 BswV, BswOA, BswO, fbias, value, AccSw);
    front_gemm_kernel<<<MT_TILES * 2, 256, 0, stream>>>(inflat, query, BswV, BswOA,
                                                        bv, fbias, value, fused, M);
    msda_sample_kernel<<<QBLKS * 8, 256, 0, stream>>>(refp, value, fused, AccSw);
    back_gemm_kernel<<<MT_TILES, 256, 0, stream>>>(AccSw, BswO, bout, out, M);
}

// Round 3
// 195.004 us; speedup vs baseline: 1.1829x; 1.1374x over previous
//
#include <hip/hip_runtime.h>

#define NH 8
#define HD 32
#define NL 4
#define NP 4
#define DM 256
#define LEN_IN_C 13294
#define LQ_C 13294
#define B_C 2
#define M_TOTAL (B_C * LQ_C)           // 26588
#define MT_TILES 1662                  // ceil(26588/16)
#define RT32_TILES 831                 // ceil(26588/32)
#define GQ 32                          // queries per sampler block
#define QBLKS 831                      // ceil(26588/32)

typedef __attribute__((ext_vector_type(8))) short short8;
typedef __attribute__((ext_vector_type(4))) float floatx4;
typedef __attribute__((ext_vector_type(2))) float floatx2;

__device__ __forceinline__ unsigned short f2bf(float x) {
    union { float f; unsigned int u; } a; a.f = x;
    unsigned int r = (a.u + 0x7FFFu + ((a.u >> 16) & 1u)) >> 16;
    return (unsigned short)r;
}
__device__ __forceinline__ floatx2 up2(unsigned int u) {
    union { unsigned int u; float f; } lo, hi;
    lo.u = u << 16; hi.u = u & 0xffff0000u;
    floatx2 r; r.x = lo.f; r.y = hi.f; return r;
}
__device__ __forceinline__ unsigned int cvtpk_bf16(float lo, float hi) {
    unsigned int r;
    asm("v_cvt_pk_bf16_f32 %0, %1, %2" : "=v"(r) : "v"(lo), "v"(hi));
    return r;
}

// ---------------------------------------------------------------------------
// Weight conversions + bias fuse + pad/tail zeroing in ONE kernel.
// ---------------------------------------------------------------------------
__device__ __forceinline__ void conv_b_body(const float* __restrict__ W,
                                            unsigned short* __restrict__ Bsw,
                                            int Nsrc, int NTsrc, int NTtotal, int ntOff,
                                            int vblk) {
    const int u = vblk * 256 + threadIdx.x;
    const int lane = u & 63;
    const int unit = u >> 6;
    const int ntl = unit % NTsrc;
    const int kc = unit / NTsrc;
    const int n = ntl * 16 + (lane & 15);
    const int k0 = kc * 32 + (lane >> 4) * 8;
    short8 v;
#pragma unroll
    for (int j = 0; j < 8; ++j)
        v[j] = (short)f2bf(W[(size_t)(k0 + j) * Nsrc + n]);
    ((short8*)Bsw)[(size_t)(kc * NTtotal + ntOff + ntl) * 64 + lane] = v;
}

__global__ __launch_bounds__(256) void conv_weights_kernel(const float* __restrict__ Wv,
                                                           const float* __restrict__ Woff,
                                                           const float* __restrict__ Wattn,
                                                           const float* __restrict__ Wout,
                                                           const float* __restrict__ boff,
                                                           const float* __restrict__ battn,
                                                           unsigned short* __restrict__ BswV,
                                                           unsigned short* __restrict__ BswOA,
                                                           unsigned short* __restrict__ BswO,
                                                           float* __restrict__ fbias,
                                                           unsigned short* __restrict__ value,
                                                           unsigned short* __restrict__ AccSw) {
    const int blk = blockIdx.x;
    if (blk < 32)        conv_b_body(Wv,    BswV,  256, 16, 16, 0,  blk);
    else if (blk < 64)   conv_b_body(Woff,  BswOA, 256, 16, 24, 0,  blk - 32);
    else if (blk < 80)   conv_b_body(Wattn, BswOA, 128,  8, 24, 16, blk - 64);
    else if (blk < 112)  conv_b_body(Wout,  BswO,  256, 16, 16, 0,  blk - 80);
    else if (blk < 114) {
        const int t = (blk - 112) * 256 + threadIdx.x;
        if (t < 384) fbias[t] = (t < 256) ? boff[t] : battn[t - 256];
        else if (t < 416) {
            const int j = t - 384;
            value[-32 + j] = 0;                            // front pad (64 B)
            value[(size_t)M_TOTAL * 256 + j] = 0;          // back pad (64 B)
        }
    } else {
        // zero the tail rows 26588..26591 of AccSw (rt=1661, m=12..15)
        const int idx = threadIdx.x;
        if (idx < 128) {
            const int kc = idx >> 4;
            const int sub = idx & 15;
            const int lane = (12 + (sub & 3)) + 16 * (sub >> 2);
            const size_t unit = (size_t)(1661 * 8 + kc) * 64 + lane;
            short8 z = (short8){0, 0, 0, 0, 0, 0, 0, 0};
            ((short8*)AccSw)[unit] = z;
        }
    }
}

// ---------------------------------------------------------------------------
// Front GEMM body with LDS-staged A.
//   Stage: 32x256 fp32 tile -> bf16 LDS (16 KB), coalesced float4 loads,
//          cvt_pk once, XOR-swizzle byte ^= (row&7)<<4 so the row-per-lane
//          fragment ds_read_b128s are <=2-way bank conflicted.
//   MFMA:  2 row-tiles x 8 kc x NTW, B fragments streamed from L2.
// OUTMODE 0: fp32 row-major [M, NT*16].  OUTMODE 1: bf16 head-major value
//   layout value[((b*8+h)*LEN + pos)*32 + d].
// ---------------------------------------------------------------------------
template <int NT, int OUTMODE>
__device__ __forceinline__ void gemm_lds_full(unsigned short* __restrict__ sA,
                                              const float* __restrict__ A,
                                              const unsigned short* __restrict__ Bsw,
                                              const float* __restrict__ bias,
                                              void* __restrict__ Cout, int M, int rt32) {
    constexpr int NTW = NT / 4;
    const int tid = threadIdx.x;
    const int lane = tid & 63;
    const int wave = tid >> 6;
    const int trow = rt32 * 32;

    // ---- stage A tile (coalesced, bf16, swizzled) ----
#pragma unroll
    for (int i = 0; i < 8; ++i) {
        const int li = i * 1024 + tid * 4;          // float index within tile
        const int lrow = li >> 8;
        const int lcol = li & 255;
        const int srow = min(trow + lrow, M - 1);
        const float4 f = *(const float4*)(A + (size_t)srow * 256 + lcol);
        uint2 pk;
        pk.x = cvtpk_bf16(f.x, f.y);
        pk.y = cvtpk_bf16(f.z, f.w);
        const int lb = (li * 2) ^ ((lrow & 7) << 4);
        *(uint2*)((char*)sA + lb) = pk;
    }
    __syncthreads();

    const int m = lane & 15;
    const int q = lane >> 4;
    const short8* Bu = (const short8*)Bsw;

    floatx4 acc[2][NTW];
#pragma unroll
    for (int r = 0; r < 2; ++r)
#pragma unroll
        for (int t = 0; t < NTW; ++t) acc[r][t] = (floatx4){0.f, 0.f, 0.f, 0.f};

    const int swz = (m & 7) << 4;
#pragma unroll 2
    for (int kc = 0; kc < 8; ++kc) {
        const int fb0 = (m * 512 + kc * 64 + q * 16) ^ swz;
        const int fb1 = ((m + 16) * 512 + kc * 64 + q * 16) ^ swz;
        const short8 a0 = *(const short8*)((const char*)sA + fb0);
        const short8 a1 = *(const short8*)((const char*)sA + fb1);
#pragma unroll
        for (int t = 0; t < NTW; ++t) {
            const short8 b = Bu[(size_t)(kc * NT + wave * NTW + t) * 64 + lane];
            acc[0][t] = __builtin_amdgcn_mfma_f32_16x16x32_bf16(a0, b, acc[0][t], 0, 0, 0);
            acc[1][t] = __builtin_amdgcn_mfma_f32_16x16x32_bf16(a1, b, acc[1][t], 0, 0, 0);
        }
    }

    const int N = NT * 16;
    const int colq = lane & 15;
    const int rowq = (lane >> 4) * 4;
#pragma unroll
    for (int t = 0; t < NTW; ++t) {
        const int col = (wave * NTW + t) * 16 + colq;
        const float bc = bias[col];
#pragma unroll
        for (int r = 0; r < 2; ++r) {
#pragma unroll
            for (int reg = 0; reg < 4; ++reg) {
                const int row = trow + r * 16 + rowq + reg;
                if (row < M) {
                    const float v = acc[r][t][reg] + bc;
                    if (OUTMODE == 1) {
                        const int bb = row >= LEN_IN_C;
                        const int pos = row - (bb ? LEN_IN_C : 0);
                        const int hh = col >> 5;
                        const int dd = col & 31;
                        ((unsigned short*)Cout)[((size_t)((bb << 3) + hh) * LEN_IN_C + pos) * 32 + dd] = f2bf(v);
                    } else {
                        ((float*)Cout)[(size_t)row * N + col] = v;
                    }
                }
            }
        }
    }
}

// Combined front GEMM: even blocks -> value projection, odd -> off/attn GEMM.
__global__ __launch_bounds__(256) void front_gemm_kernel(const float* __restrict__ inflat,
                                                         const float* __restrict__ query,
                                                         const unsigned short* __restrict__ BswV,
                                                         const unsigned short* __restrict__ BswOA,
                                                         const float* __restrict__ bv,
                                                         const float* __restrict__ fbias,
                                                         unsigned short* __restrict__ value,
                                                         float* __restrict__ fused, int M) {
    __shared__ unsigned short sA[32 * 256];       // 16 KB
    const int x = blockIdx.x;
    const int rt32 = x >> 1;
    if ((x & 1) == 0)
        gemm_lds_full<16, 1>(sA, inflat, BswV, bv, (void*)value, M, rt32);
    else
        gemm_lds_full<24, 0>(sA, query, BswOA, fbias, (void*)fused, M, rt32);
}

// ---------------------------------------------------------------------------
// Back GEMM: pre-swizzled bf16 A (sampler output), one 16-row tile per block.
// ---------------------------------------------------------------------------
__global__ __launch_bounds__(256) void back_gemm_kernel(const unsigned short* __restrict__ Asw,
                                                        const unsigned short* __restrict__ Bsw,
                                                        const float* __restrict__ bias,
                                                        float* __restrict__ Cout, int M) {
    constexpr int NT = 16;
    constexpr int NTW = 4;
    const int tid = threadIdx.x;
    const int lane = tid & 63;
    const int wave = tid >> 6;
    const int rt = blockIdx.x;

    const short8* Au = (const short8*)Asw;
    const short8* Bu = (const short8*)Bsw;

    floatx4 acc[NTW];
#pragma unroll
    for (int t = 0; t < NTW; ++t) acc[t] = (floatx4){0.f, 0.f, 0.f, 0.f};

#pragma unroll 2
    for (int kc = 0; kc < 8; ++kc) {
        const short8 a = Au[(size_t)(rt * 8 + kc) * 64 + lane];
#pragma unroll
        for (int t = 0; t < NTW; ++t) {
            const short8 b = Bu[(size_t)(kc * NT + wave * NTW + t) * 64 + lane];
            acc[t] = __builtin_amdgcn_mfma_f32_16x16x32_bf16(a, b, acc[t], 0, 0, 0);
        }
    }

    const int colq = lane & 15;
    const int rowq = (lane >> 4) * 4;
#pragma unroll
    for (int t = 0; t < NTW; ++t) {
        const int col = (wave * NTW + t) * 16 + colq;
        const float bc = bias[col];
#pragma unroll
        for (int reg = 0; reg < 4; ++reg) {
            const int row = rt * 16 + rowq + reg;
            if (row < M)
                Cout[(size_t)row * 256 + col] = acc[t][reg] + bc;
        }
    }
}

// ---------------------------------------------------------------------------
// Sampler v5: head-per-XCD partitioning (unchanged from round 2).
// ---------------------------------------------------------------------------
__global__ __launch_bounds__(256, 8) void msda_sample_kernel(const float* __restrict__ refp,
                                                             const unsigned short* __restrict__ value,
                                                             const float* __restrict__ fused,
                                                             unsigned short* __restrict__ AccSw) {
    constexpr int lvl_hw[4] = {100, 50, 25, 13};
    constexpr int lvl_s[4] = {0, 10000, 12500, 13125};

    const int wg = blockIdx.x;
    const int h = wg & 7;
    const int q0 = (wg >> 3) * GQ;
    const int tid = threadIdx.x;

    __shared__ float s_ref[GQ * 8];
    __shared__ int2 s_pi[GQ * 17];
    __shared__ float4 s_pw[GQ * 17];

    s_ref[tid] = refp[min(q0 * 8 + tid, M_TOTAL * 8 - 1)];
    __syncthreads();

#pragma unroll
    for (int jj = 0; jj < 2; ++jj) {
        const int job = jj * 256 + tid;          // 0..511
        const int qq = job >> 4;                 // 0..31
        const int t16 = job & 15;                // l*4+p
        const int l = t16 >> 2;
        const int bq = min(q0 + qq, M_TOTAL - 1);
        const int b = (bq >= LQ_C) ? 1 : 0;

        // softmax over the 16 (l,p) logits of head h (16 consecutive lanes)
        const float logit = fused[(size_t)bq * 384 + 256 + h * 16 + t16];
        float m = logit;
#pragma unroll
        for (int mask = 1; mask < 16; mask <<= 1) m = fmaxf(m, __shfl_xor(m, mask));
        const float e = expf(logit - m);
        float s = e;
#pragma unroll
        for (int mask = 1; mask < 16; mask <<= 1) s += __shfl_xor(s, mask);
        const float aw = e / s;

        const int whl = lvl_hw[l];
        const float fwh = (float)whl;
        const float2 oxy = *(const float2*)(fused + (size_t)bq * 384 + (h * 16 + t16) * 2);
        const float x = s_ref[qq * 8 + l * 2] * fwh + oxy.x - 0.5f;
        const float y = s_ref[qq * 8 + l * 2 + 1] * fwh + oxy.y - 0.5f;
        const float x0f = floorf(x), y0f = floorf(y);
        const float tx = x - x0f, ty = y - y0f;
        const int ix0 = (int)x0f, iy0 = (int)y0f;

        const bool xv0 = (unsigned)ix0 < (unsigned)whl;
        const bool xv1 = (unsigned)(ix0 + 1) < (unsigned)whl;
        const bool yv0 = (unsigned)iy0 < (unsigned)whl;
        const bool yv1 = (unsigned)(iy0 + 1) < (unsigned)whl;

        // pair base x: clamp to [-1, w-1]; invalid halves carry zero weight
        const int cxp = min(max(ix0, -1), whl - 1);
        const int cy0 = min(max(iy0, 0), whl - 1);
        const int cy1 = min(max(iy0 + 1, 0), whl - 1);

        const int posb = (b * 8 + h) * LEN_IN_C + lvl_s[l];
        int2 aa;                                  // BYTE offsets of 128-B pairs
        aa.x = (posb + cy0 * whl + cxp) * 64;
        aa.y = (posb + cy1 * whl + cxp) * 64;
        float4 wv;
        wv.x = (xv0 && yv0) ? aw * (1.f - tx) * (1.f - ty) : 0.f;
        wv.y = (xv1 && yv0) ? aw * tx * (1.f - ty) : 0.f;
        wv.z = (xv0 && yv1) ? aw * (1.f - tx) * ty : 0.f;
        wv.w = (xv1 && yv1) ? aw * tx * ty : 0.f;
        const int slot = qq * 17 + t16;
        s_pi[slot] = aa;
        s_pw[slot] = wv;
    }
    __syncthreads();

    const int qq = tid >> 3;
    const int l8 = tid & 7;
    const char* vbp = (const char*)value + l8 * 16;
    const int pbase = qq * 17;
    const bool right = (l8 & 4) != 0;

    floatx2 acc0 = (floatx2){0.f, 0.f}, acc1 = acc0, acc2 = acc0, acc3 = acc0;
#pragma unroll 2
    for (int pt = 0; pt < 16; ++pt) {
        const int2 aa = s_pi[pbase + pt];
        const float4 wv = s_pw[pbase + pt];
        const float wt = right ? wv.y : wv.x;
        const float wb = right ? wv.w : wv.z;
        const uint4 vt = *(const uint4*)(vbp + aa.x);
        const uint4 vbm = *(const uint4*)(vbp + aa.y);
        const floatx2 w2t = (floatx2){wt, wt};
        const floatx2 w2b = (floatx2){wb, wb};
        acc0 += w2t * up2(vt.x);
        acc1 += w2t * up2(vt.y);
        acc2 += w2t * up2(vt.z);
        acc3 += w2t * up2(vt.w);
        acc0 += w2b * up2(vbm.x);
        acc1 += w2b * up2(vbm.y);
        acc2 += w2b * up2(vbm.z);
        acc3 += w2b * up2(vbm.w);
    }

    float r0 = acc0.x, r1 = acc0.y, r2 = acc1.x, r3 = acc1.y;
    float r4 = acc2.x, r5 = acc2.y, r6 = acc3.x, r7 = acc3.y;
    r0 += __shfl_xor(r0, 4); r1 += __shfl_xor(r1, 4);
    r2 += __shfl_xor(r2, 4); r3 += __shfl_xor(r3, 4);
    r4 += __shfl_xor(r4, 4); r5 += __shfl_xor(r5, 4);
    r6 += __shfl_xor(r6, 4); r7 += __shfl_xor(r7, 4);

    const int bq = q0 + qq;
    if (!right && bq < M_TOTAL) {
        // write swizzled A-fragment: row = bq, col = h*32 + (l8&3)*8 (+0..7)
        const int rt = bq >> 4, mm = bq & 15;
        const int unit = (rt * 8 + h) * 64 + ((l8 & 3) * 16 + mm);
        uint4 o;
        o.x = cvtpk_bf16(r0, r1);
        o.y = cvtpk_bf16(r2, r3);
        o.z = cvtpk_bf16(r4, r5);
        o.w = cvtpk_bf16(r6, r7);
        *(uint4*)(AccSw + (size_t)unit * 8) = o;
    }
}

extern "C" void kernel_launch(void* const* d_in, const int* in_sizes, int n_in,
                              void* d_out, int out_size, void* d_ws, size_t ws_size,
                              hipStream_t stream) {
    const float* query  = (const float*)d_in[0];
    const float* refp   = (const float*)d_in[1];
    const float* inflat = (const float*)d_in[2];
    const float* Wv    = (const float*)d_in[4];
    const float* bv    = (const float*)d_in[5];
    const float* Woff  = (const float*)d_in[6];
    const float* boff  = (const float*)d_in[7];
    const float* Wattn = (const float*)d_in[8];
    const float* battn = (const float*)d_in[9];
    const float* Wout  = (const float*)d_in[10];
    const float* bout  = (const float*)d_in[11];
    float* out = (float*)d_out;

    char* p = (char*)d_ws;
    unsigned short* AccSw = (unsigned short*)p;
    p += (size_t)MT_TILES * 8 * 64 * 8 * sizeof(unsigned short);          // 13.6 MB
    unsigned short* BswV = (unsigned short*)p;   p += (size_t)8 * 16 * 64 * 8 * 2;
    unsigned short* BswOA = (unsigned short*)p;  p += (size_t)8 * 24 * 64 * 8 * 2;
    unsigned short* BswO = (unsigned short*)p;   p += (size_t)8 * 16 * 64 * 8 * 2;
    float* fbias = (float*)p;                    p += 384 * sizeof(float);
    unsigned short* value = (unsigned short*)p + 32;                      // 64 B front pad
    p += ((size_t)M_TOTAL * 256 + 64) * sizeof(unsigned short);           // + 64 B back pad
    float* fused = (float*)p;                    p += (size_t)M_TOTAL * 384 * 4;

    const int M = M_TOTAL;

    conv_weights_kernel<<<115, 256, 0, stream>>>(Wv, Woff, Wattn, Wout, boff, battn,
                                                 BswV, BswOA, BswO, fbias, value, AccSw);
    front_gemm_kernel<<<RT32_TILES * 2, 256, 0, stream>>>(inflat, query, BswV, BswOA,
                                                          bv, fbias, value, fused, M);
    msda_sample_kernel<<<QBLKS * 8, 256, 0, stream>>>(refp, value, fused, AccSw);
    back_gemm_kernel<<<MT_TILES, 256, 0, stream>>>(AccSw, BswO, bout, out, M);
}

// Round 4
// 193.368 us; speedup vs baseline: 1.1929x; 1.0085x over previous
//
#include <hip/hip_runtime.h>

#define NH 8
#define HD 32
#define NL 4
#define NP 4
#define DM 256
#define LEN_IN_C 13294
#define LQ_C 13294
#define B_C 2
#define M_TOTAL (B_C * LQ_C)           // 26588
#define MT_TILES 1662                  // ceil(26588/16)
#define RT32_TILES 831                 // ceil(26588/32)
#define VB64 416                       // ceil(26588/64) value-GEMM 64-row tiles
#define GQ 32                          // queries per sampler block
#define QBLKS 831                      // ceil(26588/32)

typedef __attribute__((ext_vector_type(8))) short short8;
typedef __attribute__((ext_vector_type(4))) float floatx4;

__device__ __forceinline__ unsigned short f2bf(float x) {
    union { float f; unsigned int u; } a; a.f = x;
    unsigned int r = (a.u + 0x7FFFu + ((a.u >> 16) & 1u)) >> 16;
    return (unsigned short)r;
}
__device__ __forceinline__ unsigned short f2h(float x) {
    unsigned int r;
    asm("v_cvt_f16_f32 %0, %1" : "=v"(r) : "v"(x));
    return (unsigned short)r;
}
__device__ __forceinline__ unsigned int cvtpk_bf16(float lo, float hi) {
    unsigned int r;
    asm("v_cvt_pk_bf16_f32 %0, %1, %2" : "=v"(r) : "v"(lo), "v"(hi));
    return r;
}

// acc += f16(lo/hi half of v) * w   — one VALU op, f32 accumulate.
#define FMAMIX_LO(acc, v, w) \
    asm("v_fma_mix_f32 %0, %1, %2, %0 op_sel_hi:[1,0,0]" : "+v"(acc) : "v"(v), "v"(w))
#define FMAMIX_HI(acc, v, w) \
    asm("v_fma_mix_f32 %0, %1, %2, %0 op_sel:[1,0,0] op_sel_hi:[1,0,0]" : "+v"(acc) : "v"(v), "v"(w))

// ---------------------------------------------------------------------------
// Weight conversions + bias fuse + pad/tail zeroing in ONE kernel.
// ---------------------------------------------------------------------------
__device__ __forceinline__ void conv_b_body(const float* __restrict__ W,
                                            unsigned short* __restrict__ Bsw,
                                            int Nsrc, int NTsrc, int NTtotal, int ntOff,
                                            int vblk) {
    const int u = vblk * 256 + threadIdx.x;
    const int lane = u & 63;
    const int unit = u >> 6;
    const int ntl = unit % NTsrc;
    const int kc = unit / NTsrc;
    const int n = ntl * 16 + (lane & 15);
    const int k0 = kc * 32 + (lane >> 4) * 8;
    short8 v;
#pragma unroll
    for (int j = 0; j < 8; ++j)
        v[j] = (short)f2bf(W[(size_t)(k0 + j) * Nsrc + n]);
    ((short8*)Bsw)[(size_t)(kc * NTtotal + ntOff + ntl) * 64 + lane] = v;
}

__global__ __launch_bounds__(256) void conv_weights_kernel(const float* __restrict__ Wv,
                                                           const float* __restrict__ Woff,
                                                           const float* __restrict__ Wattn,
                                                           const float* __restrict__ Wout,
                                                           const float* __restrict__ boff,
                                                           const float* __restrict__ battn,
                                                           unsigned short* __restrict__ BswV,
                                                           unsigned short* __restrict__ BswOA,
                                                           unsigned short* __restrict__ BswO,
                                                           float* __restrict__ fbias,
                                                           unsigned short* __restrict__ value,
                                                           unsigned short* __restrict__ AccSw) {
    const int blk = blockIdx.x;
    if (blk < 32)        conv_b_body(Wv,    BswV,  256, 16, 16, 0,  blk);
    else if (blk < 64)   conv_b_body(Woff,  BswOA, 256, 16, 24, 0,  blk - 32);
    else if (blk < 80)   conv_b_body(Wattn, BswOA, 128,  8, 24, 16, blk - 64);
    else if (blk < 112)  conv_b_body(Wout,  BswO,  256, 16, 16, 0,  blk - 80);
    else if (blk < 114) {
        const int t = (blk - 112) * 256 + threadIdx.x;
        if (t < 384) fbias[t] = (t < 256) ? boff[t] : battn[t - 256];
        else if (t < 416) {
            const int j = t - 384;
            value[-32 + j] = 0;                            // front pad (64 B)
            value[(size_t)M_TOTAL * 256 + j] = 0;          // back pad (64 B)
        }
    } else {
        // zero the tail rows 26588..26591 of AccSw (rt=1661, m=12..15)
        const int idx = threadIdx.x;
        if (idx < 128) {
            const int kc = idx >> 4;
            const int sub = idx & 15;
            const int lane = (12 + (sub & 3)) + 16 * (sub >> 2);
            const size_t unit = (size_t)(1661 * 8 + kc) * 64 + lane;
            short8 z = (short8){0, 0, 0, 0, 0, 0, 0, 0};
            ((short8*)AccSw)[unit] = z;
        }
    }
}

// ---------------------------------------------------------------------------
// Front GEMM body with LDS-staged A, RT row-tiles (RT*16 rows) per block.
//   Stage: RT*16 x 256 fp32 -> bf16 LDS, coalesced float4 loads, cvt_pk,
//          XOR-swizzle byte ^= (row&7)<<4 for conflict-free ds_read_b128.
//   MFMA:  RT row-frags x 8 kc x NTW; B from L2; RT MFMA per B-load.
// OUTMODE 0: fp32 row-major [M, NT*16].  OUTMODE 1: FP16 head-major value
//   layout value[((b*8+h)*LEN + pos)*32 + d].
// ---------------------------------------------------------------------------
template <int NT, int OUTMODE, int RT>
__device__ __forceinline__ void gemm_lds_full(unsigned short* __restrict__ sA,
                                              const float* __restrict__ A,
                                              const unsigned short* __restrict__ Bsw,
                                              const float* __restrict__ bias,
                                              void* __restrict__ Cout, int M, int rtb) {
    constexpr int NTW = NT / 4;
    constexpr int ROWS = RT * 16;
    const int tid = threadIdx.x;
    const int lane = tid & 63;
    const int wave = tid >> 6;
    const int trow = rtb * ROWS;

    // ---- stage A tile (coalesced, bf16, swizzled) ----
#pragma unroll
    for (int i = 0; i < RT * 4; ++i) {
        const int li = i * 1024 + tid * 4;          // float index within tile
        const int lrow = li >> 8;
        const int lcol = li & 255;
        const int srow = min(trow + lrow, M - 1);
        const float4 f = *(const float4*)(A + (size_t)srow * 256 + lcol);
        uint2 pk;
        pk.x = cvtpk_bf16(f.x, f.y);
        pk.y = cvtpk_bf16(f.z, f.w);
        const int lb = (li * 2) ^ ((lrow & 7) << 4);
        *(uint2*)((char*)sA + lb) = pk;
    }
    __syncthreads();

    const int m = lane & 15;
    const int q = lane >> 4;
    const short8* Bu = (const short8*)Bsw;

    floatx4 acc[RT][NTW];
#pragma unroll
    for (int r = 0; r < RT; ++r)
#pragma unroll
        for (int t = 0; t < NTW; ++t) acc[r][t] = (floatx4){0.f, 0.f, 0.f, 0.f};

    const int swz = (m & 7) << 4;
#pragma unroll 2
    for (int kc = 0; kc < 8; ++kc) {
        short8 a[RT];
#pragma unroll
        for (int r = 0; r < RT; ++r) {
            const int fb = ((m + r * 16) * 512 + kc * 64 + q * 16) ^ swz;
            a[r] = *(const short8*)((const char*)sA + fb);
        }
#pragma unroll
        for (int t = 0; t < NTW; ++t) {
            const short8 b = Bu[(size_t)(kc * NT + wave * NTW + t) * 64 + lane];
#pragma unroll
            for (int r = 0; r < RT; ++r)
                acc[r][t] = __builtin_amdgcn_mfma_f32_16x16x32_bf16(a[r], b, acc[r][t], 0, 0, 0);
        }
    }

    const int N = NT * 16;
    const int colq = lane & 15;
    const int rowq = (lane >> 4) * 4;
#pragma unroll
    for (int t = 0; t < NTW; ++t) {
        const int col = (wave * NTW + t) * 16 + colq;
        const float bc = bias[col];
#pragma unroll
        for (int r = 0; r < RT; ++r) {
#pragma unroll
            for (int reg = 0; reg < 4; ++reg) {
                const int row = trow + r * 16 + rowq + reg;
                if (row < M) {
                    const float v = acc[r][t][reg] + bc;
                    if (OUTMODE == 1) {
                        const int bb = row >= LEN_IN_C;
                        const int pos = row - (bb ? LEN_IN_C : 0);
                        const int hh = col >> 5;
                        const int dd = col & 31;
                        ((unsigned short*)Cout)[((size_t)((bb << 3) + hh) * LEN_IN_C + pos) * 32 + dd] = f2h(v);
                    } else {
                        ((float*)Cout)[(size_t)row * N + col] = v;
                    }
                }
            }
        }
    }
}

// Combined front GEMM: blocks [0,VB64) -> value projection (64-row tiles),
// blocks [VB64, VB64+831) -> off/attn GEMM (32-row tiles).
__global__ __launch_bounds__(256) void front_gemm_kernel(const float* __restrict__ inflat,
                                                         const float* __restrict__ query,
                                                         const unsigned short* __restrict__ BswV,
                                                         const unsigned short* __restrict__ BswOA,
                                                         const float* __restrict__ bv,
                                                         const float* __restrict__ fbias,
                                                         unsigned short* __restrict__ value,
                                                         float* __restrict__ fused, int M) {
    __shared__ unsigned short sA[64 * 256];       // 32 KB
    const int x = blockIdx.x;
    if (x < VB64)
        gemm_lds_full<16, 1, 4>(sA, inflat, BswV, bv, (void*)value, M, x);
    else
        gemm_lds_full<24, 0, 2>(sA, query, BswOA, fbias, (void*)fused, M, x - VB64);
}

// ---------------------------------------------------------------------------
// Back GEMM: pre-swizzled bf16 A (sampler output), TWO 16-row tiles per block
// (8 MFMA per 4 B-loads; 831 blocks).
// ---------------------------------------------------------------------------
__global__ __launch_bounds__(256) void back_gemm_kernel(const unsigned short* __restrict__ Asw,
                                                        const unsigned short* __restrict__ Bsw,
                                                        const float* __restrict__ bias,
                                                        float* __restrict__ Cout, int M) {
    constexpr int NT = 16;
    constexpr int NTW = 4;
    const int tid = threadIdx.x;
    const int lane = tid & 63;
    const int wave = tid >> 6;
    const int rt0 = blockIdx.x * 2;

    const short8* Au = (const short8*)Asw;
    const short8* Bu = (const short8*)Bsw;

    floatx4 acc[2][NTW];
#pragma unroll
    for (int r = 0; r < 2; ++r)
#pragma unroll
        for (int t = 0; t < NTW; ++t) acc[r][t] = (floatx4){0.f, 0.f, 0.f, 0.f};

#pragma unroll 2
    for (int kc = 0; kc < 8; ++kc) {
        const short8 a0 = Au[(size_t)(rt0 * 8 + kc) * 64 + lane];
        const short8 a1 = Au[(size_t)((rt0 + 1) * 8 + kc) * 64 + lane];
#pragma unroll
        for (int t = 0; t < NTW; ++t) {
            const short8 b = Bu[(size_t)(kc * NT + wave * NTW + t) * 64 + lane];
            acc[0][t] = __builtin_amdgcn_mfma_f32_16x16x32_bf16(a0, b, acc[0][t], 0, 0, 0);
            acc[1][t] = __builtin_amdgcn_mfma_f32_16x16x32_bf16(a1, b, acc[1][t], 0, 0, 0);
        }
    }

    const int colq = lane & 15;
    const int rowq = (lane >> 4) * 4;
#pragma unroll
    for (int t = 0; t < NTW; ++t) {
        const int col = (wave * NTW + t) * 16 + colq;
        const float bc = bias[col];
#pragma unroll
        for (int r = 0; r < 2; ++r) {
#pragma unroll
            for (int reg = 0; reg < 4; ++reg) {
                const int row = (rt0 + r) * 16 + rowq + reg;
                if (row < M)
                    Cout[(size_t)row * 256 + col] = acc[r][t][reg] + bc;
            }
        }
    }
}

// ---------------------------------------------------------------------------
// Sampler v6: head-per-XCD partitioning + FP16 value + v_fma_mix_f32.
//   One block = 32 queries x 1 head; head = wgid % 8 -> XCD-private L2 slice.
//   Phase 1: 512 point-jobs: softmax over the head's 16 logits + 2 row-pair
//     byte offsets + per-SIDE (top,bot) premult weight float2s.
//   Phase 2: tid = qq*8 + l8; 8 lanes x dwordx4 = 128 B = both horizontal
//     corners of one row (f16). v_fma_mix_f32 accumulates f16 halves into
//     8 f32 scalars (1 op/MAC, f32 weights); shfl_xor(4) fold; one uint4
//     store into swizzled bf16 A-fragment layout.
// ---------------------------------------------------------------------------
__global__ __launch_bounds__(256, 8) void msda_sample_kernel(const float* __restrict__ refp,
                                                             const unsigned short* __restrict__ value,
                                                             const float* __restrict__ fused,
                                                             unsigned short* __restrict__ AccSw) {
    constexpr int lvl_hw[4] = {100, 50, 25, 13};
    constexpr int lvl_s[4] = {0, 10000, 12500, 13125};

    const int wg = blockIdx.x;
    const int h = wg & 7;
    const int q0 = (wg >> 3) * GQ;
    const int tid = threadIdx.x;

    __shared__ float s_ref[GQ * 8];
    __shared__ int2 s_pi[GQ * 17];
    __shared__ float2 s_pw2[2][GQ * 17];

    s_ref[tid] = refp[min(q0 * 8 + tid, M_TOTAL * 8 - 1)];
    __syncthreads();

#pragma unroll
    for (int jj = 0; jj < 2; ++jj) {
        const int job = jj * 256 + tid;          // 0..511
        const int qq = job >> 4;                 // 0..31
        const int t16 = job & 15;                // l*4+p
        const int l = t16 >> 2;
        const int bq = min(q0 + qq, M_TOTAL - 1);
        const int b = (bq >= LQ_C) ? 1 : 0;

        // softmax over the 16 (l,p) logits of head h (16 consecutive lanes)
        const float logit = fused[(size_t)bq * 384 + 256 + h * 16 + t16];
        float m = logit;
#pragma unroll
        for (int mask = 1; mask < 16; mask <<= 1) m = fmaxf(m, __shfl_xor(m, mask));
        const float e = expf(logit - m);
        float s = e;
#pragma unroll
        for (int mask = 1; mask < 16; mask <<= 1) s += __shfl_xor(s, mask);
        const float aw = e / s;

        const int whl = lvl_hw[l];
        const float fwh = (float)whl;
        const float2 oxy = *(const float2*)(fused + (size_t)bq * 384 + (h * 16 + t16) * 2);
        const float x = s_ref[qq * 8 + l * 2] * fwh + oxy.x - 0.5f;
        const float y = s_ref[qq * 8 + l * 2 + 1] * fwh + oxy.y - 0.5f;
        const float x0f = floorf(x), y0f = floorf(y);
        const float tx = x - x0f, ty = y - y0f;
        const int ix0 = (int)x0f, iy0 = (int)y0f;

        const bool xv0 = (unsigned)ix0 < (unsigned)whl;
        const bool xv1 = (unsigned)(ix0 + 1) < (unsigned)whl;
        const bool yv0 = (unsigned)iy0 < (unsigned)whl;
        const bool yv1 = (unsigned)(iy0 + 1) < (unsigned)whl;

        // pair base x: clamp to [-1, w-1]; invalid halves carry zero weight
        const int cxp = min(max(ix0, -1), whl - 1);
        const int cy0 = min(max(iy0, 0), whl - 1);
        const int cy1 = min(max(iy0 + 1, 0), whl - 1);

        const int posb = (b * 8 + h) * LEN_IN_C + lvl_s[l];
        int2 aa;                                  // BYTE offsets of 128-B pairs
        aa.x = (posb + cy0 * whl + cxp) * 64;
        aa.y = (posb + cy1 * whl + cxp) * 64;
        const float w00 = (xv0 && yv0) ? aw * (1.f - tx) * (1.f - ty) : 0.f;
        const float w01 = (xv1 && yv0) ? aw * tx * (1.f - ty) : 0.f;
        const float w10 = (xv0 && yv1) ? aw * (1.f - tx) * ty : 0.f;
        const float w11 = (xv1 && yv1) ? aw * tx * ty : 0.f;
        const int slot = qq * 17 + t16;
        s_pi[slot] = aa;
        s_pw2[0][slot] = make_float2(w00, w10);   // left corner: (top, bottom)
        s_pw2[1][slot] = make_float2(w01, w11);   // right corner: (top, bottom)
    }
    __syncthreads();

    const int qq = tid >> 3;
    const int l8 = tid & 7;
    const char* vbp = (const char*)value + l8 * 16;
    const int pbase = qq * 17;
    const int side = (l8 >> 2) & 1;

    float a0 = 0.f, a1 = 0.f, a2 = 0.f, a3 = 0.f;
    float a4 = 0.f, a5 = 0.f, a6 = 0.f, a7 = 0.f;
#pragma unroll 2
    for (int pt = 0; pt < 16; ++pt) {
        const int2 aa = s_pi[pbase + pt];
        const float2 ww = s_pw2[side][pbase + pt];    // (w_top, w_bot)
        const uint4 vt = *(const uint4*)(vbp + aa.x);
        const uint4 vb = *(const uint4*)(vbp + aa.y);
        FMAMIX_LO(a0, vt.x, ww.x); FMAMIX_HI(a1, vt.x, ww.x);
        FMAMIX_LO(a2, vt.y, ww.x); FMAMIX_HI(a3, vt.y, ww.x);
        FMAMIX_LO(a4, vt.z, ww.x); FMAMIX_HI(a5, vt.z, ww.x);
        FMAMIX_LO(a6, vt.w, ww.x); FMAMIX_HI(a7, vt.w, ww.x);
        FMAMIX_LO(a0, vb.x, ww.y); FMAMIX_HI(a1, vb.x, ww.y);
        FMAMIX_LO(a2, vb.y, ww.y); FMAMIX_HI(a3, vb.y, ww.y);
        FMAMIX_LO(a4, vb.z, ww.y); FMAMIX_HI(a5, vb.z, ww.y);
        FMAMIX_LO(a6, vb.w, ww.y); FMAMIX_HI(a7, vb.w, ww.y);
    }

    a0 += __shfl_xor(a0, 4); a1 += __shfl_xor(a1, 4);
    a2 += __shfl_xor(a2, 4); a3 += __shfl_xor(a3, 4);
    a4 += __shfl_xor(a4, 4); a5 += __shfl_xor(a5, 4);
    a6 += __shfl_xor(a6, 4); a7 += __shfl_xor(a7, 4);

    const int bq = q0 + qq;
    if (side == 0 && bq < M_TOTAL) {
        // write swizzled A-fragment: row = bq, col = h*32 + (l8&3)*8 (+0..7)
        const int rt = bq >> 4, mm = bq & 15;
        const int unit = (rt * 8 + h) * 64 + ((l8 & 3) * 16 + mm);
        uint4 o;
        o.x = cvtpk_bf16(a0, a1);
        o.y = cvtpk_bf16(a2, a3);
        o.z = cvtpk_bf16(a4, a5);
        o.w = cvtpk_bf16(a6, a7);
        *(uint4*)(AccSw + (size_t)unit * 8) = o;
    }
}

extern "C" void kernel_launch(void* const* d_in, const int* in_sizes, int n_in,
                              void* d_out, int out_size, void* d_ws, size_t ws_size,
                              hipStream_t stream) {
    const float* query  = (const float*)d_in[0];
    const float* refp   = (const float*)d_in[1];
    const float* inflat = (const float*)d_in[2];
    const float* Wv    = (const float*)d_in[4];
    const float* bv    = (const float*)d_in[5];
    const float* Woff  = (const float*)d_in[6];
    const float* boff  = (const float*)d_in[7];
    const float* Wattn = (const float*)d_in[8];
    const float* battn = (const float*)d_in[9];
    const float* Wout  = (const float*)d_in[10];
    const float* bout  = (const float*)d_in[11];
    float* out = (float*)d_out;

    char* p = (char*)d_ws;
    unsigned short* AccSw = (unsigned short*)p;
    p += (size_t)MT_TILES * 8 * 64 * 8 * sizeof(unsigned short);          // 13.6 MB
    unsigned short* BswV = (unsigned short*)p;   p += (size_t)8 * 16 * 64 * 8 * 2;
    unsigned short* BswOA = (unsigned short*)p;  p += (size_t)8 * 24 * 64 * 8 * 2;
    unsigned short* BswO = (unsigned short*)p;   p += (size_t)8 * 16 * 64 * 8 * 2;
    float* fbias = (float*)p;                    p += 384 * sizeof(float);
    unsigned short* value = (unsigned short*)p + 32;                      // 64 B front pad
    p += ((size_t)M_TOTAL * 256 + 64) * sizeof(unsigned short);           // + 64 B back pad
    float* fused = (float*)p;                    p += (size_t)M_TOTAL * 384 * 4;

    const int M = M_TOTAL;

    conv_weights_kernel<<<115, 256, 0, stream>>>(Wv, Woff, Wattn, Wout, boff, battn,
                                                 BswV, BswOA, BswO, fbias, value, AccSw);
    front_gemm_kernel<<<VB64 + RT32_TILES, 256, 0, stream>>>(inflat, query, BswV, BswOA,
                                                             bv, fbias, value, fused, M);
    msda_sample_kernel<<<QBLKS * 8, 256, 0, stream>>>(refp, value, fused, AccSw);
    back_gemm_kernel<<<RT32_TILES, 256, 0, stream>>>(AccSw, BswO, bout, out, M);
}